// Round 13
// baseline (235.399 us; speedup 1.0000x reference)
//
#include <hip/hip_runtime.h>

#define T_TOK 16384
#define H_DIM 4096
#define O_DIM 4096
#define NA 8
#define RANK 16
#define CHUNK 256            // f32 cols staged per chunk (phase 1)
#define LROW 260             // padded LDS row stride
#define NCH (H_DIM / CHUNK)  // 16 chunks

typedef float f32x4 __attribute__((ext_vector_type(4)));
typedef short bf16x8 __attribute__((ext_vector_type(8)));

struct ushort4s { unsigned short x, y, z, w; };

// f32 -> bf16 (RTNE)
static __device__ __forceinline__ unsigned short f2bf(float f) {
    unsigned int u = __float_as_uint(f);
    u = (u + 0x7fffu + ((u >> 16) & 1u)) >> 16;
    return (unsigned short)u;
}
static __device__ __forceinline__ float bf2f(unsigned short s) {
    return __uint_as_float(((unsigned int)s) << 16);
}

// async global->LDS, 16B per lane, dest = wave-uniform base + lane*16
#define GL2LDS(gsrc, ldst)                                                   \
    __builtin_amdgcn_global_load_lds(                                        \
        (const __attribute__((address_space(1))) unsigned int*)(gsrc),       \
        (__attribute__((address_space(3))) unsigned int*)(ldst), 16, 0, 0)

// ---------------- setup: zero + hist + prefix in ONE kernel ----------------

__global__ void k_setup(const int* __restrict__ idx, int* __restrict__ counts,
                        int* __restrict__ offs, int* __restrict__ cursor) {
    __shared__ int h[NA];
    if (threadIdx.x < NA) h[threadIdx.x] = 0;
    __syncthreads();
    for (int i = threadIdx.x; i < T_TOK; i += 256)
        atomicAdd(&h[idx[i]], 1);
    __syncthreads();
    if (threadIdx.x == 0) {
        int run = 0;
        for (int n = 0; n < NA; ++n) {
            counts[n] = h[n]; offs[n] = run; cursor[n] = run; run += h[n];
        }
    }
}

__global__ void k_scatter(const int* __restrict__ idx, int* __restrict__ cursor,
                          int* __restrict__ order) {
    int t = blockIdx.x * blockDim.x + threadIdx.x;
    int a = idx[t];
    int lane = threadIdx.x & 63;
    for (int n = 0; n < NA; n++) {
        unsigned long long m = __ballot(a == n);
        if (m) {
            int leader = __ffsll((unsigned long long)m) - 1;
            int cnt = __popcll(m);
            int base = 0;
            if (lane == leader) base = atomicAdd(&cursor[n], cnt);
            base = __shfl(base, leader);
            if (a == n) {
                int rank = __popcll(m & ((1ull << lane) - 1ull));
                order[base + rank] = t;
            }
        }
    }
}

// ---------------- transpose A -> ATb[n][r][h] (bf16) ----------------

__global__ void k_transpose(const float* __restrict__ A, unsigned short* __restrict__ ATb) {
    const int n = blockIdx.y;
    const int h0 = blockIdx.x * 256;
    __shared__ float lds[256 * 17];
    const float4* src = (const float4*)(A + ((size_t)n * H_DIM + h0) * RANK);
#pragma unroll
    for (int k = 0; k < 4; ++k) {
        int f = k * 256 + threadIdx.x;
        float4 v = src[f];
        int row = (f * 4) >> 4, col = (f * 4) & 15;
        lds[row * 17 + col + 0] = v.x;
        lds[row * 17 + col + 1] = v.y;
        lds[row * 17 + col + 2] = v.z;
        lds[row * 17 + col + 3] = v.w;
    }
    __syncthreads();
    unsigned short* dst = ATb + (size_t)n * RANK * H_DIM;
#pragma unroll
    for (int r = 0; r < RANK; ++r)
        dst[(size_t)r * H_DIM + h0 + threadIdx.x] = f2bf(lds[threadIdx.x * 17 + r]);
}

// ---------------- fused: per 16-token tile, async MFMA shrink + LDS-B expand ----------------
// LDS union: phase 1 uses it as xs[2][16][260] f32 (33.3 KB, global_load_lds
// double-buffer); phase 2 reuses it as blds[16][1024] bf16 (32 KB).
// vp/vsum/toks live outside the union. ~38.5 KB total -> 3 blocks/CU at (256,3).

__global__ __launch_bounds__(256, 3) void k_fused(
    const float* __restrict__ result, const float* __restrict__ x,
    const unsigned short* __restrict__ atb, const float* __restrict__ lora_b,
    const int* __restrict__ order, const int* __restrict__ counts,
    const int* __restrict__ offs, float* __restrict__ out) {

    // block -> (adapter n, tile)
    const int bid = blockIdx.x;
    int n = 0, tile = 0, found = 0, acc_t = 0;
#pragma unroll
    for (int i = 0; i < NA; ++i) {
        int tn = (counts[i] + 15) >> 4;
        if (!found && bid < acc_t + tn) { n = i; tile = bid - acc_t; found = 1; }
        acc_t += tn;
    }
    if (!found) return;
    const int cnt = counts[n];
    const int seg = offs[n];
    const int tbase = tile << 4;
    const int np = min(16, cnt - tbase);

    __shared__ __align__(16) char un[2 * 16 * LROW * 4];     // 33.3 KB union
    __shared__ float vp[4][16][16];                          // 4 KB
    __shared__ float vsum[16][16];                           // 1 KB
    __shared__ int toks[16];

    float (*xs)[16][LROW] = (float (*)[16][LROW])un;         // phase 1 view
    unsigned short (*blds)[1024] = (unsigned short (*)[1024])un;  // phase 2 view

    const int w = threadIdx.x >> 6, lane = threadIdx.x & 63;
    const int mi = lane & 15, kg = lane >> 4;

    if (threadIdx.x < 16)
        toks[threadIdx.x] = order[seg + min(tbase + (int)threadIdx.x, cnt - 1)];

    // ================= phase 1: shrink =================
    {
        int tok_i[4];
#pragma unroll
        for (int i = 0; i < 4; ++i)
            tok_i[i] = order[seg + min(tbase + w * 4 + i, cnt - 1)];

        const unsigned short* bp0 = atb + ((size_t)n * RANK + mi) * H_DIM + kg * 8;

#define STAGE(c_, b_)                                                         \
    {                                                                         \
        _Pragma("unroll") for (int i_ = 0; i_ < 4; ++i_) {                    \
            const int rr_ = w * 4 + i_;                                       \
            const float* src_ =                                               \
                x + (size_t)tok_i[i_] * H_DIM + (c_) * CHUNK + (lane << 2);   \
            GL2LDS(src_, &xs[b_][rr_][0]);                                    \
        }                                                                     \
    }

        f32x4 acc = {0.f, 0.f, 0.f, 0.f};
        STAGE(0, 0);
        __syncthreads();
        for (int c = 0; c < NCH; ++c) {
            if (c + 1 < NCH) STAGE(c + 1, (c + 1) & 1);
            const int b = c & 1;
            const int cb = w * 64;
#pragma unroll
            for (int ks = 0; ks < 2; ++ks) {
                const float* lsrc = &xs[b][mi][cb + ks * 32 + kg * 8];
                f32x4 xlo = *(const f32x4*)lsrc;
                f32x4 xhi = *(const f32x4*)(lsrc + 4);
                bf16x8 bfrag = *(const bf16x8*)(bp0 + (size_t)c * CHUNK + cb + ks * 32);
                bf16x8 afrag;
                afrag[0] = (short)f2bf(xlo.x); afrag[1] = (short)f2bf(xlo.y);
                afrag[2] = (short)f2bf(xlo.z); afrag[3] = (short)f2bf(xlo.w);
                afrag[4] = (short)f2bf(xhi.x); afrag[5] = (short)f2bf(xhi.y);
                afrag[6] = (short)f2bf(xhi.z); afrag[7] = (short)f2bf(xhi.w);
                acc = __builtin_amdgcn_mfma_f32_16x16x32_bf16(afrag, bfrag, acc, 0, 0, 0);
            }
            __syncthreads();   // drains stage(c+1); xs[b] reuse safe
        }
#undef STAGE

#pragma unroll
        for (int q = 0; q < 4; ++q)
            vp[w][kg * 4 + q][mi] = acc[q];
    }
    __syncthreads();
    {
        const int p = threadIdx.x >> 4, r = threadIdx.x & 15;
        vsum[p][r] = (vp[0][p][r] + vp[1][p][r]) + (vp[2][p][r] + vp[3][p][r]);
    }
    // no barrier needed yet: the staging below writes the union (xs region),
    // which no thread reads anymore; the next __syncthreads covers vsum+blds.

    // ================= phase 2: expand, 4 col-quarters =================
    const float* Bn = lora_b + (size_t)n * RANK * O_DIM;
#pragma unroll 1
    for (int q = 0; q < 4; ++q) {
        // stage B quarter as bf16 (coalesced per rank row, L2-hot)
#pragma unroll
        for (int r = 0; r < RANK; ++r) {
            f32x4 v = *(const f32x4*)(Bn + (size_t)r * O_DIM + q * 1024 + (threadIdx.x << 2));
            ushort4s u;
            u.x = f2bf(v.x); u.y = f2bf(v.y); u.z = f2bf(v.z); u.w = f2bf(v.w);
            *(ushort4s*)&blds[r][threadIdx.x << 2] = u;
        }
        __syncthreads();

        const int o0 = q * 1024 + (threadIdx.x << 2);
        size_t offA = (size_t)toks[0] * O_DIM + o0;
        f32x4 rA = __builtin_nontemporal_load((const f32x4*)(result + offA));
        size_t offB = offA, offC = offA;
        f32x4 rB = rA, rC = rA;
        if (np > 1) {
            offB = (size_t)toks[1] * O_DIM + o0;
            rB = __builtin_nontemporal_load((const f32x4*)(result + offB));
        }
        if (np > 2) {
            offC = (size_t)toks[2] * O_DIM + o0;
            rC = __builtin_nontemporal_load((const f32x4*)(result + offC));
        }

        for (int p = 0; p < np; ++p) {
            f32x4 rD = rC;
            size_t offD = 0;
            if (p + 3 < np) {
                offD = (size_t)toks[p + 3] * O_DIM + o0;
                rD = __builtin_nontemporal_load((const f32x4*)(result + offD));
            }
            float va[RANK];
#pragma unroll
            for (int u = 0; u < 4; ++u)
                *(f32x4*)&va[u * 4] = *(const f32x4*)&vsum[p][u * 4];
            f32x4 acc = rA;
#pragma unroll
            for (int r = 0; r < RANK; ++r) {
                ushort4s u = *(const ushort4s*)&blds[r][threadIdx.x << 2];
                acc.x = fmaf(va[r], bf2f(u.x), acc.x);
                acc.y = fmaf(va[r], bf2f(u.y), acc.y);
                acc.z = fmaf(va[r], bf2f(u.z), acc.z);
                acc.w = fmaf(va[r], bf2f(u.w), acc.w);
            }
            __builtin_nontemporal_store(acc, (f32x4*)(out + offA));
            rA = rB; offA = offB;
            rB = rC; offB = offC;
            rC = rD; offC = offD;
        }
        if (q + 1 < 4) __syncthreads();   // before restaging blds
    }
}

// ---------------- launch ----------------

extern "C" void kernel_launch(void* const* d_in, const int* in_sizes, int n_in,
                              void* d_out, int out_size, void* d_ws, size_t ws_size,
                              hipStream_t stream) {
    const float* result = (const float*)d_in[0];
    const float* x      = (const float*)d_in[1];
    const float* lora_a = (const float*)d_in[2];
    const float* lora_b = (const float*)d_in[3];
    const int*   aidx   = (const int*)d_in[4];
    float* out = (float*)d_out;

    int* order  = (int*)d_ws;
    int* counts = order + T_TOK;
    int* offs   = counts + NA;
    int* cursor = offs + NA;
    unsigned short* ATb = (unsigned short*)(cursor + NA);        // 1 MB

    k_setup<<<dim3(1), dim3(256), 0, stream>>>(aidx, counts, offs, cursor);
    k_scatter<<<dim3(64), dim3(256), 0, stream>>>(aidx, cursor, order);
    k_transpose<<<dim3(16, NA), dim3(256), 0, stream>>>(lora_a, ATb);
    k_fused<<<dim3(T_TOK / 16 + NA), dim3(256), 0, stream>>>(
        result, x, ATb, lora_b, order, counts, offs, out);
}